// Round 1
// baseline (1069.152 us; speedup 1.0000x reference)
//
#include <hip/hip_runtime.h>

typedef __bf16 bf16_t;
typedef __attribute__((ext_vector_type(8))) __bf16 bf16x8;
typedef __attribute__((ext_vector_type(4))) float f32x4;

#define GLD16(gptr, lptr)                                                              \
  __builtin_amdgcn_global_load_lds((const __attribute__((address_space(1))) void*)(gptr), \
                                   (__attribute__((address_space(3))) void*)(lptr), 16, 0, 0)

__device__ __forceinline__ float gelu_f(float x) {
  return 0.5f * x * (1.0f + erff(x * 0.7071067811865476f));
}

// ---------------------------------------------------------------------------
// f32 -> bf16 convert (vectorized, grid-stride). n8 = count of 8-elem groups.
// ---------------------------------------------------------------------------
__global__ __launch_bounds__(256) void conv_bf16(const float* __restrict__ in,
                                                 bf16_t* __restrict__ out, int n8) {
  for (int idx = blockIdx.x * 256 + threadIdx.x; idx < n8; idx += gridDim.x * 256) {
    const float4* p = reinterpret_cast<const float4*>(in + (size_t)idx * 8);
    float4 a = p[0], b = p[1];
    bf16x8 v;
    v[0] = (bf16_t)a.x; v[1] = (bf16_t)a.y; v[2] = (bf16_t)a.z; v[3] = (bf16_t)a.w;
    v[4] = (bf16_t)b.x; v[5] = (bf16_t)b.y; v[6] = (bf16_t)b.z; v[7] = (bf16_t)b.w;
    *reinterpret_cast<bf16x8*>(out + (size_t)idx * 8) = v;
  }
}

// ---------------------------------------------------------------------------
// Tiled transpose + f32->bf16: dst[n*dstStride + k] = src[k*N + n]
// grid = (K/64)*(N/64), block 256.
// ---------------------------------------------------------------------------
__global__ __launch_bounds__(256) void transpose_conv(const float* __restrict__ src,
                                                      bf16_t* __restrict__ dst, int K,
                                                      int N, int dstStride) {
  __shared__ float lds[64][65];
  const int ntn = N >> 6;
  const int tile = blockIdx.x;
  const int tk = tile / ntn, tn = tile % ntn;
  const int k0 = tk << 6, n0 = tn << 6;
  const int t = threadIdx.x;
#pragma unroll
  for (int q = 0; q < 16; q++) {
    int idx = q * 256 + t;
    int kk = idx >> 6, nn = idx & 63;
    lds[kk][nn] = src[(size_t)(k0 + kk) * N + n0 + nn];
  }
  __syncthreads();
#pragma unroll
  for (int q = 0; q < 16; q++) {
    int idx = q * 256 + t;
    int nn = idx >> 6, kk = idx & 63;
    dst[(size_t)(n0 + nn) * dstStride + k0 + kk] = (bf16_t)lds[kk][nn];
  }
}

// ---------------------------------------------------------------------------
// m97-style bf16 GEMM, C = A(MxK) * BT(NxK)^T. 128x128 tile, 4 waves, BK=32.
// EPI 0: C[row,col] = acc (f32)
// EPI 1: C[row,col] = (acc + bias[col]) * rowscale[row]
// ---------------------------------------------------------------------------
template <int EPI>
__global__ __launch_bounds__(256) void gemm_bt(const bf16_t* __restrict__ A,
                                               const bf16_t* __restrict__ BT,
                                               float* __restrict__ C,
                                               const float* __restrict__ bias,
                                               const float* __restrict__ rowscale,
                                               int M, int N, int K) {
  __shared__ bf16_t As[128 * 32];
  __shared__ bf16_t Bs[128 * 32];

  const int nbn = N >> 7;
  const int nwg = gridDim.x;
  int bid = blockIdx.x;
  const int cpx = nwg >> 3;  // nwg % 8 == 0 guaranteed by launch
  bid = (bid & 7) * cpx + (bid >> 3);
  const int tm = bid / nbn, tn = bid % nbn;
  const int m0 = tm << 7, n0 = tn << 7;

  const int t = threadIdx.x;
  const int lane = t & 63, wid = t >> 6;
  const int wm = (wid >> 1) << 6, wn = (wid & 1) << 6;
  const int fr = lane & 15;
  const int krow = (lane >> 4) << 3;

  f32x4 acc[4][4] = {};

  const int sr = t >> 2;
  const int sc = (t & 3) << 3;
  const bf16_t* ga = A + (size_t)(m0 + sr) * K + sc;
  const bf16_t* gb = BT + (size_t)(n0 + sr) * K + sc;
  bf16_t* lA0 = &As[wid * 512];
  bf16_t* lA1 = &As[2048 + wid * 512];
  bf16_t* lB0 = &Bs[wid * 512];
  bf16_t* lB1 = &Bs[2048 + wid * 512];
  const size_t rowskip = (size_t)64 * K;

  for (int k0 = 0; k0 < K; k0 += 32) {
    GLD16(ga + k0, lA0);
    GLD16(ga + rowskip + k0, lA1);
    GLD16(gb + k0, lB0);
    GLD16(gb + rowskip + k0, lB1);
    __syncthreads();
    bf16x8 af[4], bfr[4];
#pragma unroll
    for (int f = 0; f < 4; f++) {
      af[f] = *reinterpret_cast<const bf16x8*>(&As[(wm + f * 16 + fr) * 32 + krow]);
      bfr[f] = *reinterpret_cast<const bf16x8*>(&Bs[(wn + f * 16 + fr) * 32 + krow]);
    }
#pragma unroll
    for (int i = 0; i < 4; i++)
#pragma unroll
      for (int j = 0; j < 4; j++)
        acc[i][j] = __builtin_amdgcn_mfma_f32_16x16x32_bf16(af[i], bfr[j], acc[i][j], 0, 0, 0);
    __syncthreads();
  }

  const int r0 = (lane >> 4) << 2;
#pragma unroll
  for (int i = 0; i < 4; i++) {
    const int rowb = m0 + wm + i * 16 + r0;
#pragma unroll
    for (int j = 0; j < 4; j++) {
      const int col = n0 + wn + j * 16 + fr;
#pragma unroll
      for (int r = 0; r < 4; r++) {
        float v = acc[i][j][r];
        const int row = rowb + r;
        if (EPI == 1) v = (v + bias[col]) * rowscale[row];
        C[(size_t)row * N + col] = v;
      }
    }
  }
}

// ---------------------------------------------------------------------------
// Row epilogue after GEMM1: X[row, 0:2048]   -> gelu -> LN -> L2-normalize -> Nrm (bf16)
//                            X[row, 2048:4096]-> gelu(imp*x + b_d1)         -> Hbuf (bf16)
// one block (256 thr) per row; each thread owns 8 contiguous cols per half.
// ---------------------------------------------------------------------------
__global__ __launch_bounds__(256) void epilogue1(const float* __restrict__ X,
                                                 const float* __restrict__ imp,
                                                 const float* __restrict__ b_sim,
                                                 const float* __restrict__ ln_g,
                                                 const float* __restrict__ ln_b,
                                                 const float* __restrict__ b_d1,
                                                 bf16_t* __restrict__ Nrm,
                                                 bf16_t* __restrict__ Hbuf) {
  __shared__ float red[8];
  const int row = blockIdx.x;
  const int t = threadIdx.x;
  const int lane = t & 63, wid = t >> 6;
  const float* xr = X + (size_t)row * 4096;
  const int c0 = t * 8;

  float g[8];
  float s1 = 0.f, s2 = 0.f;
  {
    const float4* p = reinterpret_cast<const float4*>(xr + c0);
    float4 a = p[0], b = p[1];
    float xv[8] = {a.x, a.y, a.z, a.w, b.x, b.y, b.z, b.w};
#pragma unroll
    for (int q = 0; q < 8; q++) {
      float v = xv[q] + b_sim[c0 + q];
      float gv = gelu_f(v);
      g[q] = gv;
      s1 += gv;
      s2 += gv * gv;
    }
  }
#pragma unroll
  for (int o = 32; o > 0; o >>= 1) {
    s1 += __shfl_down(s1, o);
    s2 += __shfl_down(s2, o);
  }
  if (lane == 0) { red[wid] = s1; red[4 + wid] = s2; }
  __syncthreads();
  s1 = red[0] + red[1] + red[2] + red[3];
  s2 = red[4] + red[5] + red[6] + red[7];
  __syncthreads();

  const float mu = s1 * (1.0f / 2048.0f);
  const float var = s2 * (1.0f / 2048.0f) - mu * mu;
  const float rstd = rsqrtf(var + 1e-5f);

  float y[8];
  float s3 = 0.f;
#pragma unroll
  for (int q = 0; q < 8; q++) {
    float yv = (g[q] - mu) * rstd * ln_g[c0 + q] + ln_b[c0 + q];
    y[q] = yv;
    s3 += yv * yv;
  }
#pragma unroll
  for (int o = 32; o > 0; o >>= 1) s3 += __shfl_down(s3, o);
  if (lane == 0) red[wid] = s3;
  __syncthreads();
  s3 = red[0] + red[1] + red[2] + red[3];

  const float scale = 1.0f / (sqrtf(s3) + 1e-8f);
  bf16x8 nv;
#pragma unroll
  for (int q = 0; q < 8; q++) nv[q] = (bf16_t)(y[q] * scale);
  *reinterpret_cast<bf16x8*>(Nrm + (size_t)row * 2048 + c0) = nv;

  const float ir = imp[row];
  const float4* p2 = reinterpret_cast<const float4*>(xr + 2048 + c0);
  float4 a2 = p2[0], b2 = p2[1];
  float xv2[8] = {a2.x, a2.y, a2.z, a2.w, b2.x, b2.y, b2.z, b2.w};
  bf16x8 hv;
#pragma unroll
  for (int q = 0; q < 8; q++) {
    float v = xv2[q] * ir + b_d1[c0 + q];
    hv[q] = (bf16_t)gelu_f(v);
  }
  *reinterpret_cast<bf16x8*>(Hbuf + (size_t)row * 2048 + c0) = hv;
}

// ---------------------------------------------------------------------------
// Batched sim GEMM over lower-triangular 128x128 tiles; emits condition bits
// cond[b][i][jw] (bit j-in-word set iff sim>0.85 && imp[j]>=imp[i] && j<i).
// grid = 8 batches * 36 tiles.
// ---------------------------------------------------------------------------
__global__ __launch_bounds__(256) void sim_gemm(const bf16_t* __restrict__ Nrm,
                                                const float* __restrict__ imp,
                                                unsigned long long* __restrict__ cond) {
  __shared__ bf16_t As[128 * 32];
  __shared__ bf16_t Bs[128 * 32];

  const int b = blockIdx.x / 36;
  const int tt = blockIdx.x % 36;
  int ti = 0;
  while ((ti + 1) * (ti + 2) / 2 <= tt) ti++;
  const int tj = tt - ti * (ti + 1) / 2;

  const bf16_t* Ab = Nrm + (size_t)b * 1024 * 2048;
  const int K = 2048;
  const int m0 = ti << 7, n0 = tj << 7;

  const int t = threadIdx.x;
  const int lane = t & 63, wid = t >> 6;
  const int wm = (wid >> 1) << 6, wn = (wid & 1) << 6;
  const int fr = lane & 15;
  const int krow = (lane >> 4) << 3;

  f32x4 acc[4][4] = {};

  const int sr = t >> 2;
  const int sc = (t & 3) << 3;
  const bf16_t* ga = Ab + (size_t)(m0 + sr) * K + sc;
  const bf16_t* gb = Ab + (size_t)(n0 + sr) * K + sc;
  bf16_t* lA0 = &As[wid * 512];
  bf16_t* lA1 = &As[2048 + wid * 512];
  bf16_t* lB0 = &Bs[wid * 512];
  bf16_t* lB1 = &Bs[2048 + wid * 512];
  const size_t rowskip = (size_t)64 * K;

  for (int k0 = 0; k0 < K; k0 += 32) {
    GLD16(ga + k0, lA0);
    GLD16(ga + rowskip + k0, lA1);
    GLD16(gb + k0, lB0);
    GLD16(gb + rowskip + k0, lB1);
    __syncthreads();
    bf16x8 af[4], bfr[4];
#pragma unroll
    for (int f = 0; f < 4; f++) {
      af[f] = *reinterpret_cast<const bf16x8*>(&As[(wm + f * 16 + fr) * 32 + krow]);
      bfr[f] = *reinterpret_cast<const bf16x8*>(&Bs[(wn + f * 16 + fr) * 32 + krow]);
    }
#pragma unroll
    for (int i = 0; i < 4; i++)
#pragma unroll
      for (int j = 0; j < 4; j++)
        acc[i][j] = __builtin_amdgcn_mfma_f32_16x16x32_bf16(af[i], bfr[j], acc[i][j], 0, 0, 0);
    __syncthreads();
  }

  const float* impb = imp + b * 1024;
  const int jw = (n0 + wn) >> 6;
  unsigned long long* crow = cond + (size_t)b * 1024 * 16;
  const int g = lane >> 4;
#pragma unroll
  for (int fm = 0; fm < 4; fm++) {
#pragma unroll
    for (int r = 0; r < 4; r++) {
      const int i = m0 + wm + fm * 16 + g * 4 + r;
      const float impi = impb[i];
      unsigned long long w0 = 0;
#pragma unroll
      for (int fn = 0; fn < 4; fn++) {
        const int j = n0 + wn + fn * 16 + fr;
        const float s = acc[fm][fn][r];
        const bool pred = (s > 0.85f) && (impb[j] >= impi) && (j < i);
        unsigned long long bal = __ballot(pred);
        w0 |= ((bal >> (g * 16)) & 0xFFFFull) << (fn * 16);
      }
      if (fr == 0) crow[(size_t)i * 16 + jw] = w0;
    }
  }
}

// ---------------------------------------------------------------------------
// Sequential greedy-keep scan. One block per batch. Writes kept mask (f32)
// to workspace (for GEMM2 row scaling) and to d_out tail.
// ---------------------------------------------------------------------------
__global__ __launch_bounds__(256) void scan_keep(const unsigned long long* __restrict__ cond,
                                                 float* __restrict__ keptF,
                                                 float* __restrict__ outMask) {
  __shared__ unsigned long long kept[16];
  __shared__ unsigned char cand[1024];
  const int b = blockIdx.x;
  const int t = threadIdx.x;
  if (t < 16) kept[t] = ~0ull;
  const unsigned long long* cb = cond + (size_t)b * 1024 * 16;

  for (int i = t; i < 1024; i += 256) {
    const int wmax = i >> 6;
    unsigned long long any = 0;
    for (int w = 0; w < wmax; w++) any |= cb[i * 16 + w];
    const unsigned long long m = (i & 63) ? ((1ull << (i & 63)) - 1ull) : 0ull;
    any |= cb[i * 16 + wmax] & m;
    cand[i] = (any != 0);
  }
  __syncthreads();

  if (t < 64) {
    for (int i = 1; i < 1024; i++) {
      if (!cand[i]) continue;
      const int wmax = i >> 6;
      unsigned long long v = 0;
      if (t <= wmax) {
        const unsigned long long m =
            (t < wmax) ? ~0ull : ((i & 63) ? ((1ull << (i & 63)) - 1ull) : 0ull);
        v = cb[i * 16 + t] & kept[t] & m;
      }
      const bool sup = __any(v != 0);
      if (sup && t == 0) kept[i >> 6] &= ~(1ull << (i & 63));
    }
  }
  __syncthreads();

  for (int i = t; i < 1024; i += 256) {
    const float kv = ((kept[i >> 6] >> (i & 63)) & 1ull) ? 1.0f : 0.0f;
    keptF[b * 1024 + i] = kv;
    outMask[b * 1024 + i] = kv;
  }
}

// ---------------------------------------------------------------------------
extern "C" void kernel_launch(void* const* d_in, const int* in_sizes, int n_in,
                              void* d_out, int out_size, void* d_ws, size_t ws_size,
                              hipStream_t stream) {
  const float* seg = (const float*)d_in[0];
  const float* imp = (const float*)d_in[1];
  const float* Wsim = (const float*)d_in[2];
  const float* bsim = (const float*)d_in[3];
  const float* lng = (const float*)d_in[4];
  const float* lnb = (const float*)d_in[5];
  const float* Wd1 = (const float*)d_in[6];
  const float* bd1 = (const float*)d_in[7];
  const float* Wd2 = (const float*)d_in[8];
  const float* bd2 = (const float*)d_in[9];

  char* w = (char*)d_ws;
  bf16_t* A1 = (bf16_t*)w;  w += (size_t)8192 * 4096 * 2;   // 64 MB
  bf16_t* W1T = (bf16_t*)w; w += (size_t)4096 * 4096 * 2;   // 32 MB
  bf16_t* W2T = (bf16_t*)w; w += (size_t)4096 * 2048 * 2;   // 16 MB
  bf16_t* Nrm = (bf16_t*)w; w += (size_t)8192 * 2048 * 2;   // 32 MB
  bf16_t* Hb = (bf16_t*)w;  w += (size_t)8192 * 2048 * 2;   // 32 MB
  unsigned long long* cond = (unsigned long long*)w; w += (size_t)8 * 1024 * 16 * 8;  // 1 MB
  float* keptF = (float*)w; w += (size_t)8192 * 4;

  float* X = (float*)d_out;  // 8192x4096 f32 scratch, overwritten by GEMM2
  float* outMask = (float*)d_out + (size_t)8192 * 4096;

  conv_bf16<<<4096, 256, 0, stream>>>(seg, A1, 8192 * 512);
  transpose_conv<<<2048, 256, 0, stream>>>(Wsim, W1T, 4096, 2048, 4096);
  transpose_conv<<<2048, 256, 0, stream>>>(Wd1, W1T + (size_t)2048 * 4096, 4096, 2048, 4096);
  transpose_conv<<<2048, 256, 0, stream>>>(Wd2, W2T, 2048, 4096, 2048);

  gemm_bt<0><<<2048, 256, 0, stream>>>(A1, W1T, X, nullptr, nullptr, 8192, 4096, 4096);
  epilogue1<<<8192, 256, 0, stream>>>(X, imp, bsim, lng, lnb, bd1, Nrm, Hb);
  sim_gemm<<<288, 256, 0, stream>>>(Nrm, imp, cond);
  scan_keep<<<8, 256, 0, stream>>>(cond, keptF, outMask);
  gemm_bt<1><<<2048, 256, 0, stream>>>(Hb, W2T, (float*)d_out, bd2, keptF, 8192, 4096, 2048);
}

// Round 2
// 843.653 us; speedup vs baseline: 1.2673x; 1.2673x over previous
//
#include <hip/hip_runtime.h>

typedef __bf16 bf16_t;
typedef __attribute__((ext_vector_type(8))) __bf16 bf16x8;
typedef __attribute__((ext_vector_type(4))) float f32x4;

#define GLD16(gptr, lptr)                                                              \
  __builtin_amdgcn_global_load_lds((const __attribute__((address_space(1))) void*)(gptr), \
                                   (__attribute__((address_space(3))) void*)(lptr), 16, 0, 0)

#define BAR() __builtin_amdgcn_s_barrier()
#define WAIT_LGKM0()                                      \
  do {                                                    \
    asm volatile("s_waitcnt lgkmcnt(0)" ::: "memory");    \
    __builtin_amdgcn_sched_barrier(0);                    \
  } while (0)
#define WAIT_VM4() asm volatile("s_waitcnt vmcnt(4)" ::: "memory")
#define WAIT_VM0() asm volatile("s_waitcnt vmcnt(0)" ::: "memory")
#define PRIO1() __builtin_amdgcn_s_setprio(1)
#define PRIO0() __builtin_amdgcn_s_setprio(0)

__device__ __forceinline__ float gelu_f(float x) {
  return 0.5f * x * (1.0f + erff(x * 0.7071067811865476f));
}

__device__ __forceinline__ void ld_a4(bf16x8 (&a)[4][2], const char* base) {
#pragma unroll
  for (int f = 0; f < 4; f++)
#pragma unroll
    for (int s = 0; s < 2; s++)
      a[f][s] = *reinterpret_cast<const bf16x8*>(base + f * 2048 + s * 64);
}

__device__ __forceinline__ void ld_b2(bf16x8 (&b)[2][2], const char* base) {
#pragma unroll
  for (int f = 0; f < 2; f++)
#pragma unroll
    for (int s = 0; s < 2; s++)
      b[f][s] = *reinterpret_cast<const bf16x8*>(base + f * 2048 + s * 64);
}

template <int MH, int NH>
__device__ __forceinline__ void mm16(f32x4 (&acc)[8][4], const bf16x8 (&a)[4][2],
                                     const bf16x8 (&b)[2][2]) {
#pragma unroll
  for (int i = 0; i < 4; i++)
#pragma unroll
    for (int j = 0; j < 2; j++)
#pragma unroll
      for (int s = 0; s < 2; s++)
        acc[MH * 4 + i][NH * 2 + j] = __builtin_amdgcn_mfma_f32_16x16x32_bf16(
            a[i][s], b[j][s], acc[MH * 4 + i][NH * 2 + j], 0, 0, 0);
}

__device__ __forceinline__ void stage2(const bf16_t* src, char* ldst, size_t rowskip) {
  GLD16(src, ldst);
  GLD16(src + rowskip, ldst + 8192);
}

// ---------------------------------------------------------------------------
// 256x256 8-phase bf16 GEMM, C = A(MxK) * BT(NxK)^T.  BK=64, 8 waves (2x4).
// LDS 128KB: A bufs at 0 (buf b half h -> (b*2+h)*16384), B at 65536.
// st_16x32 swizzle via pre-swizzled global source + swizzled ds_read.
// EPI 0: C = acc.  EPI 1: C = (acc + bias[col]) * rowscale[row].
// ---------------------------------------------------------------------------
template <int EPI>
__global__ __launch_bounds__(512, 2) void gemm256(const bf16_t* __restrict__ A,
                                                  const bf16_t* __restrict__ BT,
                                                  float* __restrict__ C,
                                                  const float* __restrict__ bias,
                                                  const float* __restrict__ rowscale,
                                                  int M, int N, int K) {
  __shared__ char smem[131072];
  const int NKT = K >> 6;
  const int niter = NKT >> 1;

  const int nbn = N >> 8;
  int bid = blockIdx.x;
  const int cpx = gridDim.x >> 3;  // nwg % 8 == 0 guaranteed by launch
  bid = (bid & 7) * cpx + (bid >> 3);
  const int m0 = (bid / nbn) << 8, n0 = (bid % nbn) << 8;

  const int t = threadIdx.x;
  const int lane = t & 63, wid = t >> 6;
  const int wr = wid >> 2, wc = wid & 3;
  const int fr = lane & 15, kq = lane >> 4;
  const int xorbit = ((fr >> 2) & 1) << 5;
  const int rdcol = (kq * 16) ^ xorbit;

  // ds_read bases (buf0); buf1 = +32768. mh half-quad: +8192, nh: +4096.
  const char* aR0 = smem + wr * 16384 + fr * 128 + rdcol;
  const char* bR0 = smem + 65536 + (wc >> 1) * 16384 + ((wc & 1) * 64 + fr) * 128 + rdcol;

  // stage source mapping: LDS dest is linear t*16; source logical byte = swz(dest)
  const int swz16 = (t * 16) ^ (((t >> 5) & 1) << 5);
  const int sr0 = swz16 >> 7;           // row 0..63 (sweep1 adds 64)
  const int scol = (swz16 & 127) >> 1;  // bf16 col 0..63
  const bf16_t* gA = A + (size_t)(m0 + sr0) * K + scol;
  const bf16_t* gB = BT + (size_t)(n0 + sr0) * K + scol;
  const size_t rskip = (size_t)64 * K;
  char* ldA = smem + t * 16;
  char* ldB = smem + 65536 + t * 16;

#define STG_A(kc, bb, h) stage2(gA + (size_t)(h)*128 * K + (size_t)(kc)*64, ldA + ((bb)*2 + (h)) * 16384, rskip)
#define STG_B(kc, bb, h) stage2(gB + (size_t)(h)*128 * K + (size_t)(kc)*64, ldB + ((bb)*2 + (h)) * 16384, rskip)

  f32x4 acc[8][4] = {};
  bf16x8 a[4][2], b0[2][2], b1[2][2];

  // prologue: c0.B, c0.A, c1.B  (12 loads; loop-top vmcnt(4) covers through c0.A1)
  STG_B(0, 0, 0); STG_B(0, 0, 1); STG_A(0, 0, 0); STG_A(0, 0, 1);
  STG_B(1, 1, 0); STG_B(1, 1, 1);

  for (int it = 0; it < niter; ++it) {
    const int c1 = 2 * it + 1;
    const int c2 = (2 * it + 2 < NKT) ? 2 * it + 2 : NKT - 1;
    const int c3 = (2 * it + 3 < NKT) ? 2 * it + 3 : NKT - 1;

    WAIT_VM4();
    BAR();
    // P1: c0 quad (0,0)
    ld_a4(a, aR0);
    ld_b2(b0, bR0);
    STG_A(c1, 1, 0);
    BAR(); WAIT_LGKM0();
    PRIO1(); mm16<0, 0>(acc, a, b0); PRIO0();
    BAR();
    // P2: (0,1)
    ld_b2(b1, bR0 + 4096);
    STG_A(c1, 1, 1);
    BAR(); WAIT_LGKM0();
    PRIO1(); mm16<0, 1>(acc, a, b1); PRIO0();
    BAR();
    // P3: (1,0)
    ld_a4(a, aR0 + 8192);
    STG_B(c2, 0, 0);
    BAR(); WAIT_LGKM0();
    PRIO1(); mm16<1, 0>(acc, a, b0); PRIO0();
    BAR();
    // P4: (1,1)
    STG_B(c2, 0, 1);
    BAR(); WAIT_LGKM0();
    PRIO1(); mm16<1, 1>(acc, a, b1); PRIO0();
    WAIT_VM4();
    BAR();
    // P5: c1 (buf1) quad (0,0)
    ld_a4(a, aR0 + 32768);
    ld_b2(b0, bR0 + 32768);
    STG_A(c2, 0, 0);
    BAR(); WAIT_LGKM0();
    PRIO1(); mm16<0, 0>(acc, a, b0); PRIO0();
    BAR();
    // P6: (0,1)
    ld_b2(b1, bR0 + 32768 + 4096);
    STG_A(c2, 0, 1);
    BAR(); WAIT_LGKM0();
    PRIO1(); mm16<0, 1>(acc, a, b1); PRIO0();
    BAR();
    // P7: (1,0)
    ld_a4(a, aR0 + 32768 + 8192);
    STG_B(c3, 1, 0);
    BAR(); WAIT_LGKM0();
    PRIO1(); mm16<1, 0>(acc, a, b0); PRIO0();
    BAR();
    // P8: (1,1)
    STG_B(c3, 1, 1);
    BAR(); WAIT_LGKM0();
    PRIO1(); mm16<1, 1>(acc, a, b1); PRIO0();
    // loop-top WAIT_VM4+BAR is the end-of-P8 sync
  }
  WAIT_VM0();

#undef STG_A
#undef STG_B

  const int r0 = kq * 4;
#pragma unroll
  for (int i = 0; i < 8; i++) {
    const int row = m0 + wr * 128 + i * 16 + r0;
#pragma unroll
    for (int j = 0; j < 4; j++) {
      const int col = n0 + wc * 64 + j * 16 + fr;
#pragma unroll
      for (int r = 0; r < 4; r++) {
        float v = acc[i][j][r];
        if (EPI == 1) v = (v + bias[col]) * rowscale[row + r];
        C[(size_t)(row + r) * N + col] = v;
      }
    }
  }
}

// ---------------------------------------------------------------------------
// f32 -> bf16 convert (vectorized, grid-stride). n8 = count of 8-elem groups.
// ---------------------------------------------------------------------------
__global__ __launch_bounds__(256) void conv_bf16(const float* __restrict__ in,
                                                 bf16_t* __restrict__ out, int n8) {
  for (int idx = blockIdx.x * 256 + threadIdx.x; idx < n8; idx += gridDim.x * 256) {
    const float4* p = reinterpret_cast<const float4*>(in + (size_t)idx * 8);
    float4 a = p[0], b = p[1];
    bf16x8 v;
    v[0] = (bf16_t)a.x; v[1] = (bf16_t)a.y; v[2] = (bf16_t)a.z; v[3] = (bf16_t)a.w;
    v[4] = (bf16_t)b.x; v[5] = (bf16_t)b.y; v[6] = (bf16_t)b.z; v[7] = (bf16_t)b.w;
    *reinterpret_cast<bf16x8*>(out + (size_t)idx * 8) = v;
  }
}

// ---------------------------------------------------------------------------
// Tiled transpose + f32->bf16: dst[n*dstStride + k] = src[k*N + n]
// ---------------------------------------------------------------------------
__global__ __launch_bounds__(256) void transpose_conv(const float* __restrict__ src,
                                                      bf16_t* __restrict__ dst, int K,
                                                      int N, int dstStride) {
  __shared__ float lds[64][65];
  const int ntn = N >> 6;
  const int tile = blockIdx.x;
  const int tk = tile / ntn, tn = tile % ntn;
  const int k0 = tk << 6, n0 = tn << 6;
  const int t = threadIdx.x;
#pragma unroll
  for (int q = 0; q < 16; q++) {
    int idx = q * 256 + t;
    int kk = idx >> 6, nn = idx & 63;
    lds[kk][nn] = src[(size_t)(k0 + kk) * N + n0 + nn];
  }
  __syncthreads();
#pragma unroll
  for (int q = 0; q < 16; q++) {
    int idx = q * 256 + t;
    int nn = idx >> 6, kk = idx & 63;
    dst[(size_t)(n0 + nn) * dstStride + k0 + kk] = (bf16_t)lds[kk][nn];
  }
}

// ---------------------------------------------------------------------------
// Row epilogue after GEMM1 (see round-1 comments).
// ---------------------------------------------------------------------------
__global__ __launch_bounds__(256) void epilogue1(const float* __restrict__ X,
                                                 const float* __restrict__ imp,
                                                 const float* __restrict__ b_sim,
                                                 const float* __restrict__ ln_g,
                                                 const float* __restrict__ ln_b,
                                                 const float* __restrict__ b_d1,
                                                 bf16_t* __restrict__ Nrm,
                                                 bf16_t* __restrict__ Hbuf) {
  __shared__ float red[8];
  const int row = blockIdx.x;
  const int t = threadIdx.x;
  const int lane = t & 63, wid = t >> 6;
  const float* xr = X + (size_t)row * 4096;
  const int c0 = t * 8;

  float g[8];
  float s1 = 0.f, s2 = 0.f;
  {
    const float4* p = reinterpret_cast<const float4*>(xr + c0);
    float4 a = p[0], b = p[1];
    float xv[8] = {a.x, a.y, a.z, a.w, b.x, b.y, b.z, b.w};
#pragma unroll
    for (int q = 0; q < 8; q++) {
      float v = xv[q] + b_sim[c0 + q];
      float gv = gelu_f(v);
      g[q] = gv;
      s1 += gv;
      s2 += gv * gv;
    }
  }
#pragma unroll
  for (int o = 32; o > 0; o >>= 1) {
    s1 += __shfl_down(s1, o);
    s2 += __shfl_down(s2, o);
  }
  if (lane == 0) { red[wid] = s1; red[4 + wid] = s2; }
  __syncthreads();
  s1 = red[0] + red[1] + red[2] + red[3];
  s2 = red[4] + red[5] + red[6] + red[7];
  __syncthreads();

  const float mu = s1 * (1.0f / 2048.0f);
  const float var = s2 * (1.0f / 2048.0f) - mu * mu;
  const float rstd = rsqrtf(var + 1e-5f);

  float y[8];
  float s3 = 0.f;
#pragma unroll
  for (int q = 0; q < 8; q++) {
    float yv = (g[q] - mu) * rstd * ln_g[c0 + q] + ln_b[c0 + q];
    y[q] = yv;
    s3 += yv * yv;
  }
#pragma unroll
  for (int o = 32; o > 0; o >>= 1) s3 += __shfl_down(s3, o);
  if (lane == 0) red[wid] = s3;
  __syncthreads();
  s3 = red[0] + red[1] + red[2] + red[3];

  const float scale = 1.0f / (sqrtf(s3) + 1e-8f);
  bf16x8 nv;
#pragma unroll
  for (int q = 0; q < 8; q++) nv[q] = (bf16_t)(y[q] * scale);
  *reinterpret_cast<bf16x8*>(Nrm + (size_t)row * 2048 + c0) = nv;

  const float ir = imp[row];
  const float4* p2 = reinterpret_cast<const float4*>(xr + 2048 + c0);
  float4 a2 = p2[0], b2 = p2[1];
  float xv2[8] = {a2.x, a2.y, a2.z, a2.w, b2.x, b2.y, b2.z, b2.w};
  bf16x8 hv;
#pragma unroll
  for (int q = 0; q < 8; q++) {
    float v = xv2[q] * ir + b_d1[c0 + q];
    hv[q] = (bf16_t)gelu_f(v);
  }
  *reinterpret_cast<bf16x8*>(Hbuf + (size_t)row * 2048 + c0) = hv;
}

// ---------------------------------------------------------------------------
// Batched sim GEMM over lower-triangular 128x128 tiles -> condition bitmasks.
// ---------------------------------------------------------------------------
__global__ __launch_bounds__(256) void sim_gemm(const bf16_t* __restrict__ Nrm,
                                                const float* __restrict__ imp,
                                                unsigned long long* __restrict__ cond) {
  __shared__ bf16_t As[128 * 32];
  __shared__ bf16_t Bs[128 * 32];

  const int b = blockIdx.x / 36;
  const int tt = blockIdx.x % 36;
  int ti = 0;
  while ((ti + 1) * (ti + 2) / 2 <= tt) ti++;
  const int tj = tt - ti * (ti + 1) / 2;

  const bf16_t* Ab = Nrm + (size_t)b * 1024 * 2048;
  const int K = 2048;
  const int m0 = ti << 7, n0 = tj << 7;

  const int t = threadIdx.x;
  const int lane = t & 63, wid = t >> 6;
  const int wm = (wid >> 1) << 6, wn = (wid & 1) << 6;
  const int fr = lane & 15;
  const int krow = (lane >> 4) << 3;

  f32x4 acc[4][4] = {};

  const int sr = t >> 2;
  const int sc = (t & 3) << 3;
  const bf16_t* ga = Ab + (size_t)(m0 + sr) * K + sc;
  const bf16_t* gb = Ab + (size_t)(n0 + sr) * K + sc;
  bf16_t* lA0 = &As[wid * 512];
  bf16_t* lA1 = &As[2048 + wid * 512];
  bf16_t* lB0 = &Bs[wid * 512];
  bf16_t* lB1 = &Bs[2048 + wid * 512];
  const size_t rowskip = (size_t)64 * K;

  for (int k0 = 0; k0 < K; k0 += 32) {
    GLD16(ga + k0, lA0);
    GLD16(ga + rowskip + k0, lA1);
    GLD16(gb + k0, lB0);
    GLD16(gb + rowskip + k0, lB1);
    __syncthreads();
    bf16x8 af[4], bfr[4];
#pragma unroll
    for (int f = 0; f < 4; f++) {
      af[f] = *reinterpret_cast<const bf16x8*>(&As[(wm + f * 16 + fr) * 32 + krow]);
      bfr[f] = *reinterpret_cast<const bf16x8*>(&Bs[(wn + f * 16 + fr) * 32 + krow]);
    }
#pragma unroll
    for (int i = 0; i < 4; i++)
#pragma unroll
      for (int j = 0; j < 4; j++)
        acc[i][j] = __builtin_amdgcn_mfma_f32_16x16x32_bf16(af[i], bfr[j], acc[i][j], 0, 0, 0);
    __syncthreads();
  }

  const float* impb = imp + b * 1024;
  const int jw = (n0 + wn) >> 6;
  unsigned long long* crow = cond + (size_t)b * 1024 * 16;
  const int g = lane >> 4;
#pragma unroll
  for (int fm = 0; fm < 4; fm++) {
#pragma unroll
    for (int r = 0; r < 4; r++) {
      const int i = m0 + wm + fm * 16 + g * 4 + r;
      const float impi = impb[i];
      unsigned long long w0 = 0;
#pragma unroll
      for (int fn = 0; fn < 4; fn++) {
        const int j = n0 + wn + fn * 16 + fr;
        const float s = acc[fm][fn][r];
        const bool pred = (s > 0.85f) && (impb[j] >= impi) && (j < i);
        unsigned long long bal = __ballot(pred);
        w0 |= ((bal >> (g * 16)) & 0xFFFFull) << (fn * 16);
      }
      if (fr == 0) crow[(size_t)i * 16 + jw] = w0;
    }
  }
}

// ---------------------------------------------------------------------------
// Sequential greedy-keep scan. One block per batch.
// ---------------------------------------------------------------------------
__global__ __launch_bounds__(256) void scan_keep(const unsigned long long* __restrict__ cond,
                                                 float* __restrict__ keptF,
                                                 float* __restrict__ outMask) {
  __shared__ unsigned long long kept[16];
  __shared__ unsigned char cand[1024];
  const int b = blockIdx.x;
  const int t = threadIdx.x;
  if (t < 16) kept[t] = ~0ull;
  const unsigned long long* cb = cond + (size_t)b * 1024 * 16;

  for (int i = t; i < 1024; i += 256) {
    const int wmax = i >> 6;
    unsigned long long any = 0;
    for (int w = 0; w < wmax; w++) any |= cb[i * 16 + w];
    const unsigned long long m = (i & 63) ? ((1ull << (i & 63)) - 1ull) : 0ull;
    any |= cb[i * 16 + wmax] & m;
    cand[i] = (any != 0);
  }
  __syncthreads();

  if (t < 64) {
    for (int i = 1; i < 1024; i++) {
      if (!cand[i]) continue;
      const int wmax = i >> 6;
      unsigned long long v = 0;
      if (t <= wmax) {
        const unsigned long long m =
            (t < wmax) ? ~0ull : ((i & 63) ? ((1ull << (i & 63)) - 1ull) : 0ull);
        v = cb[i * 16 + t] & kept[t] & m;
      }
      const bool sup = __any(v != 0);
      if (sup && t == 0) kept[i >> 6] &= ~(1ull << (i & 63));
    }
  }
  __syncthreads();

  for (int i = t; i < 1024; i += 256) {
    const float kv = ((kept[i >> 6] >> (i & 63)) & 1ull) ? 1.0f : 0.0f;
    keptF[b * 1024 + i] = kv;
    outMask[b * 1024 + i] = kv;
  }
}

// ---------------------------------------------------------------------------
extern "C" void kernel_launch(void* const* d_in, const int* in_sizes, int n_in,
                              void* d_out, int out_size, void* d_ws, size_t ws_size,
                              hipStream_t stream) {
  const float* seg = (const float*)d_in[0];
  const float* imp = (const float*)d_in[1];
  const float* Wsim = (const float*)d_in[2];
  const float* bsim = (const float*)d_in[3];
  const float* lng = (const float*)d_in[4];
  const float* lnb = (const float*)d_in[5];
  const float* Wd1 = (const float*)d_in[6];
  const float* bd1 = (const float*)d_in[7];
  const float* Wd2 = (const float*)d_in[8];
  const float* bd2 = (const float*)d_in[9];

  char* w = (char*)d_ws;
  bf16_t* A1 = (bf16_t*)w;  w += (size_t)8192 * 4096 * 2;   // 64 MB
  bf16_t* W1T = (bf16_t*)w; w += (size_t)4096 * 4096 * 2;   // 32 MB
  bf16_t* W2T = (bf16_t*)w; w += (size_t)4096 * 2048 * 2;   // 16 MB
  bf16_t* Nrm = (bf16_t*)w; w += (size_t)8192 * 2048 * 2;   // 32 MB
  bf16_t* Hb = (bf16_t*)w;  w += (size_t)8192 * 2048 * 2;   // 32 MB
  unsigned long long* cond = (unsigned long long*)w; w += (size_t)8 * 1024 * 16 * 8;  // 1 MB
  float* keptF = (float*)w; w += (size_t)8192 * 4;

  float* X = (float*)d_out;  // 8192x4096 f32 scratch, overwritten by GEMM2
  float* outMask = (float*)d_out + (size_t)8192 * 4096;

  conv_bf16<<<4096, 256, 0, stream>>>(seg, A1, 8192 * 512);
  transpose_conv<<<2048, 256, 0, stream>>>(Wsim, W1T, 4096, 2048, 4096);
  transpose_conv<<<2048, 256, 0, stream>>>(Wd1, W1T + (size_t)2048 * 4096, 4096, 2048, 4096);
  transpose_conv<<<2048, 256, 0, stream>>>(Wd2, W2T, 2048, 4096, 2048);

  gemm256<0><<<512, 512, 0, stream>>>(A1, W1T, X, nullptr, nullptr, 8192, 4096, 4096);
  epilogue1<<<8192, 256, 0, stream>>>(X, imp, bsim, lng, lnb, bd1, Nrm, Hb);
  sim_gemm<<<288, 256, 0, stream>>>(Nrm, imp, cond);
  scan_keep<<<8, 256, 0, stream>>>(cond, keptF, outMask);
  gemm256<1><<<512, 512, 0, stream>>>(Hb, W2T, (float*)d_out, bd2, keptF, 8192, 4096, 2048);
}

// Round 3
// 838.062 us; speedup vs baseline: 1.2757x; 1.0067x over previous
//
#include <hip/hip_runtime.h>

typedef __bf16 bf16_t;
typedef __attribute__((ext_vector_type(8))) __bf16 bf16x8;
typedef __attribute__((ext_vector_type(4))) float f32x4;

#define GLD16(gptr, lptr)                                                              \
  __builtin_amdgcn_global_load_lds((const __attribute__((address_space(1))) void*)(gptr), \
                                   (__attribute__((address_space(3))) void*)(lptr), 16, 0, 0)

#define BAR() __builtin_amdgcn_s_barrier()
#define WAIT_LGKM0()                                      \
  do {                                                    \
    asm volatile("s_waitcnt lgkmcnt(0)" ::: "memory");    \
    __builtin_amdgcn_sched_barrier(0);                    \
  } while (0)
#define WAIT_VM4() asm volatile("s_waitcnt vmcnt(4)" ::: "memory")
#define WAIT_VM0() asm volatile("s_waitcnt vmcnt(0)" ::: "memory")
#define PRIO1() __builtin_amdgcn_s_setprio(1)
#define PRIO0() __builtin_amdgcn_s_setprio(0)

__device__ __forceinline__ float gelu_f(float x) {
  return 0.5f * x * (1.0f + erff(x * 0.7071067811865476f));
}

// b0 = row-base + swizzled col for k-half 0, b1 = same for k-half 1 (col ^ 64)
__device__ __forceinline__ void ld_a4(bf16x8 (&a)[4][2], const char* b0, const char* b1) {
#pragma unroll
  for (int f = 0; f < 4; f++) {
    a[f][0] = *reinterpret_cast<const bf16x8*>(b0 + f * 2048);
    a[f][1] = *reinterpret_cast<const bf16x8*>(b1 + f * 2048);
  }
}

__device__ __forceinline__ void ld_b2(bf16x8 (&b)[2][2], const char* b0, const char* b1) {
#pragma unroll
  for (int f = 0; f < 2; f++) {
    b[f][0] = *reinterpret_cast<const bf16x8*>(b0 + f * 2048);
    b[f][1] = *reinterpret_cast<const bf16x8*>(b1 + f * 2048);
  }
}

template <int MH, int NH>
__device__ __forceinline__ void mm16(f32x4 (&acc)[8][4], const bf16x8 (&a)[4][2],
                                     const bf16x8 (&b)[2][2]) {
#pragma unroll
  for (int i = 0; i < 4; i++)
#pragma unroll
    for (int j = 0; j < 2; j++)
#pragma unroll
      for (int s = 0; s < 2; s++)
        acc[MH * 4 + i][NH * 2 + j] = __builtin_amdgcn_mfma_f32_16x16x32_bf16(
            a[i][s], b[j][s], acc[MH * 4 + i][NH * 2 + j], 0, 0, 0);
}

__device__ __forceinline__ void stage2(const bf16_t* src, char* ldst, size_t rowskip) {
  GLD16(src, ldst);
  GLD16(src + rowskip, ldst + 8192);
}

// ---------------------------------------------------------------------------
// 256x256 8-phase bf16 GEMM, C = A(MxK) * BT(NxK)^T.  BK=64, 8 waves (2x4).
// LDS 128KB: A bufs at 0 (buf b half h -> (b*2+h)*16384), B at 65536.
// Swizzle: byte ^= ((row&7)<<4) (permutes 16B units within each 128B row) —
// linear LDS dest + inverse-swizzled global source + swizzled ds_read.
// EPI 0: C = acc.  EPI 1: C = (acc + bias[col]) * rowscale[row].
// ---------------------------------------------------------------------------
template <int EPI>
__global__ __launch_bounds__(512, 2) void gemm256(const bf16_t* __restrict__ A,
                                                  const bf16_t* __restrict__ BT,
                                                  float* __restrict__ C,
                                                  const float* __restrict__ bias,
                                                  const float* __restrict__ rowscale,
                                                  int M, int N, int K) {
  __shared__ char smem[131072];
  const int NKT = K >> 6;
  const int niter = NKT >> 1;

  const int nbn = N >> 8;
  int bid = blockIdx.x;
  const int cpx = gridDim.x >> 3;  // nwg % 8 == 0 guaranteed by launch
  bid = (bid & 7) * cpx + (bid >> 3);
  const int m0 = (bid / nbn) << 8, n0 = (bid % nbn) << 8;

  const int t = threadIdx.x;
  const int lane = t & 63, wid = t >> 6;
  const int wr = wid >> 2, wc = wid & 3;
  const int fr = lane & 15, kq = lane >> 4;
  // swizzled column byte for k-half 0; k-half 1 = c0 ^ 64
  const int c0 = (kq ^ (fr & 7)) << 4;
  const int c1 = c0 ^ 64;

  const char* aB0 = smem + wr * 16384 + fr * 128 + c0;
  const char* aB1 = smem + wr * 16384 + fr * 128 + c1;
  const char* bB0 = smem + 65536 + (wc >> 1) * 16384 + ((wc & 1) * 64 + fr) * 128 + c0;
  const char* bB1 = smem + 65536 + (wc >> 1) * 16384 + ((wc & 1) * 64 + fr) * 128 + c1;

  // stage source mapping: LDS dest linear t*16; source byte = swz(dest) =
  // (t*16) ^ (((t>>3)&7)<<4)  (involution; row bits unchanged)
  const int sr0 = t >> 3;                              // dest row 0..63
  const int scol = ((t & 7) ^ (sr0 & 7)) * 8;          // bf16 col (swizzled unit * 8)
  const bf16_t* gA = A + (size_t)(m0 + sr0) * K + scol;
  const bf16_t* gB = BT + (size_t)(n0 + sr0) * K + scol;
  const size_t rskip = (size_t)64 * K;
  char* ldA = smem + t * 16;
  char* ldB = smem + 65536 + t * 16;

#define STG_A(kc, bb, h) stage2(gA + (size_t)(h)*128 * K + (size_t)(kc)*64, ldA + ((bb)*2 + (h)) * 16384, rskip)
#define STG_B(kc, bb, h) stage2(gB + (size_t)(h)*128 * K + (size_t)(kc)*64, ldB + ((bb)*2 + (h)) * 16384, rskip)

  f32x4 acc[8][4] = {};
  bf16x8 a[4][2], b0[2][2], b1[2][2];

  // prologue: c0.B, c0.A, c1.B  (12 loads; loop-top vmcnt(4) covers through c0.A1)
  STG_B(0, 0, 0); STG_B(0, 0, 1); STG_A(0, 0, 0); STG_A(0, 0, 1);
  STG_B(1, 1, 0); STG_B(1, 1, 1);

  for (int it = 0; it < niter; ++it) {
    const int c1k = 2 * it + 1;
    const int c2k = (2 * it + 2 < NKT) ? 2 * it + 2 : NKT - 1;
    const int c3k = (2 * it + 3 < NKT) ? 2 * it + 3 : NKT - 1;

    WAIT_VM4();
    BAR();
    // P1: c0 quad (0,0)
    ld_a4(a, aB0, aB1);
    ld_b2(b0, bB0, bB1);
    STG_A(c1k, 1, 0);
    BAR(); WAIT_LGKM0();
    PRIO1(); mm16<0, 0>(acc, a, b0); PRIO0();
    BAR();
    // P2: (0,1)
    ld_b2(b1, bB0 + 4096, bB1 + 4096);
    STG_A(c1k, 1, 1);
    BAR(); WAIT_LGKM0();
    PRIO1(); mm16<0, 1>(acc, a, b1); PRIO0();
    BAR();
    // P3: (1,0)
    ld_a4(a, aB0 + 8192, aB1 + 8192);
    STG_B(c2k, 0, 0);
    BAR(); WAIT_LGKM0();
    PRIO1(); mm16<1, 0>(acc, a, b0); PRIO0();
    BAR();
    // P4: (1,1)
    STG_B(c2k, 0, 1);
    BAR(); WAIT_LGKM0();
    PRIO1(); mm16<1, 1>(acc, a, b1); PRIO0();
    WAIT_VM4();
    BAR();
    // P5: c1 (buf1) quad (0,0)
    ld_a4(a, aB0 + 32768, aB1 + 32768);
    ld_b2(b0, bB0 + 32768, bB1 + 32768);
    STG_A(c2k, 0, 0);
    BAR(); WAIT_LGKM0();
    PRIO1(); mm16<0, 0>(acc, a, b0); PRIO0();
    BAR();
    // P6: (0,1)
    ld_b2(b1, bB0 + 36864, bB1 + 36864);
    STG_A(c2k, 0, 1);
    BAR(); WAIT_LGKM0();
    PRIO1(); mm16<0, 1>(acc, a, b1); PRIO0();
    BAR();
    // P7: (1,0)
    ld_a4(a, aB0 + 40960, aB1 + 40960);
    STG_B(c3k, 1, 0);
    BAR(); WAIT_LGKM0();
    PRIO1(); mm16<1, 0>(acc, a, b0); PRIO0();
    BAR();
    // P8: (1,1)
    STG_B(c3k, 1, 1);
    BAR(); WAIT_LGKM0();
    PRIO1(); mm16<1, 1>(acc, a, b1); PRIO0();
    // loop-top WAIT_VM4+BAR is the end-of-P8 sync
  }
  WAIT_VM0();

#undef STG_A
#undef STG_B

  const int r0 = kq * 4;
#pragma unroll
  for (int i = 0; i < 8; i++) {
    const int row = m0 + wr * 128 + i * 16 + r0;
#pragma unroll
    for (int j = 0; j < 4; j++) {
      const int col = n0 + wc * 64 + j * 16 + fr;
#pragma unroll
      for (int r = 0; r < 4; r++) {
        float v = acc[i][j][r];
        if (EPI == 1) v = (v + bias[col]) * rowscale[row + r];
        C[(size_t)(row + r) * N + col] = v;
      }
    }
  }
}

// ---------------------------------------------------------------------------
// f32 -> bf16 convert (vectorized, grid-stride). n8 = count of 8-elem groups.
// ---------------------------------------------------------------------------
__global__ __launch_bounds__(256) void conv_bf16(const float* __restrict__ in,
                                                 bf16_t* __restrict__ out, int n8) {
  for (int idx = blockIdx.x * 256 + threadIdx.x; idx < n8; idx += gridDim.x * 256) {
    const float4* p = reinterpret_cast<const float4*>(in + (size_t)idx * 8);
    float4 a = p[0], b = p[1];
    bf16x8 v;
    v[0] = (bf16_t)a.x; v[1] = (bf16_t)a.y; v[2] = (bf16_t)a.z; v[3] = (bf16_t)a.w;
    v[4] = (bf16_t)b.x; v[5] = (bf16_t)b.y; v[6] = (bf16_t)b.z; v[7] = (bf16_t)b.w;
    *reinterpret_cast<bf16x8*>(out + (size_t)idx * 8) = v;
  }
}

// ---------------------------------------------------------------------------
// Tiled transpose + f32->bf16: dst[n*dstStride + k] = src[k*N + n]
// ---------------------------------------------------------------------------
__global__ __launch_bounds__(256) void transpose_conv(const float* __restrict__ src,
                                                      bf16_t* __restrict__ dst, int K,
                                                      int N, int dstStride) {
  __shared__ float lds[64][65];
  const int ntn = N >> 6;
  const int tile = blockIdx.x;
  const int tk = tile / ntn, tn = tile % ntn;
  const int k0 = tk << 6, n0 = tn << 6;
  const int t = threadIdx.x;
#pragma unroll
  for (int q = 0; q < 16; q++) {
    int idx = q * 256 + t;
    int kk = idx >> 6, nn = idx & 63;
    lds[kk][nn] = src[(size_t)(k0 + kk) * N + n0 + nn];
  }
  __syncthreads();
#pragma unroll
  for (int q = 0; q < 16; q++) {
    int idx = q * 256 + t;
    int nn = idx >> 6, kk = idx & 63;
    dst[(size_t)(n0 + nn) * dstStride + k0 + kk] = (bf16_t)lds[kk][nn];
  }
}

// ---------------------------------------------------------------------------
// Row epilogue after GEMM1.
// ---------------------------------------------------------------------------
__global__ __launch_bounds__(256) void epilogue1(const float* __restrict__ X,
                                                 const float* __restrict__ imp,
                                                 const float* __restrict__ b_sim,
                                                 const float* __restrict__ ln_g,
                                                 const float* __restrict__ ln_b,
                                                 const float* __restrict__ b_d1,
                                                 bf16_t* __restrict__ Nrm,
                                                 bf16_t* __restrict__ Hbuf) {
  __shared__ float red[8];
  const int row = blockIdx.x;
  const int t = threadIdx.x;
  const int lane = t & 63, wid = t >> 6;
  const float* xr = X + (size_t)row * 4096;
  const int c0 = t * 8;

  float g[8];
  float s1 = 0.f, s2 = 0.f;
  {
    const float4* p = reinterpret_cast<const float4*>(xr + c0);
    float4 a = p[0], b = p[1];
    float xv[8] = {a.x, a.y, a.z, a.w, b.x, b.y, b.z, b.w};
#pragma unroll
    for (int q = 0; q < 8; q++) {
      float v = xv[q] + b_sim[c0 + q];
      float gv = gelu_f(v);
      g[q] = gv;
      s1 += gv;
      s2 += gv * gv;
    }
  }
#pragma unroll
  for (int o = 32; o > 0; o >>= 1) {
    s1 += __shfl_down(s1, o);
    s2 += __shfl_down(s2, o);
  }
  if (lane == 0) { red[wid] = s1; red[4 + wid] = s2; }
  __syncthreads();
  s1 = red[0] + red[1] + red[2] + red[3];
  s2 = red[4] + red[5] + red[6] + red[7];
  __syncthreads();

  const float mu = s1 * (1.0f / 2048.0f);
  const float var = s2 * (1.0f / 2048.0f) - mu * mu;
  const float rstd = rsqrtf(var + 1e-5f);

  float y[8];
  float s3 = 0.f;
#pragma unroll
  for (int q = 0; q < 8; q++) {
    float yv = (g[q] - mu) * rstd * ln_g[c0 + q] + ln_b[c0 + q];
    y[q] = yv;
    s3 += yv * yv;
  }
#pragma unroll
  for (int o = 32; o > 0; o >>= 1) s3 += __shfl_down(s3, o);
  if (lane == 0) red[wid] = s3;
  __syncthreads();
  s3 = red[0] + red[1] + red[2] + red[3];

  const float scale = 1.0f / (sqrtf(s3) + 1e-8f);
  bf16x8 nv;
#pragma unroll
  for (int q = 0; q < 8; q++) nv[q] = (bf16_t)(y[q] * scale);
  *reinterpret_cast<bf16x8*>(Nrm + (size_t)row * 2048 + c0) = nv;

  const float ir = imp[row];
  const float4* p2 = reinterpret_cast<const float4*>(xr + 2048 + c0);
  float4 a2 = p2[0], b2 = p2[1];
  float xv2[8] = {a2.x, a2.y, a2.z, a2.w, b2.x, b2.y, b2.z, b2.w};
  bf16x8 hv;
#pragma unroll
  for (int q = 0; q < 8; q++) {
    float v = xv2[q] * ir + b_d1[c0 + q];
    hv[q] = (bf16_t)gelu_f(v);
  }
  *reinterpret_cast<bf16x8*>(Hbuf + (size_t)row * 2048 + c0) = hv;
}

// ---------------------------------------------------------------------------
// Batched sim GEMM over lower-triangular 128x128 tiles -> condition bitmasks.
// ---------------------------------------------------------------------------
__global__ __launch_bounds__(256) void sim_gemm(const bf16_t* __restrict__ Nrm,
                                                const float* __restrict__ imp,
                                                unsigned long long* __restrict__ cond) {
  __shared__ bf16_t As[128 * 32];
  __shared__ bf16_t Bs[128 * 32];

  const int b = blockIdx.x / 36;
  const int tt = blockIdx.x % 36;
  int ti = 0;
  while ((ti + 1) * (ti + 2) / 2 <= tt) ti++;
  const int tj = tt - ti * (ti + 1) / 2;

  const bf16_t* Ab = Nrm + (size_t)b * 1024 * 2048;
  const int K = 2048;
  const int m0 = ti << 7, n0 = tj << 7;

  const int t = threadIdx.x;
  const int lane = t & 63, wid = t >> 6;
  const int wm = (wid >> 1) << 6, wn = (wid & 1) << 6;
  const int fr = lane & 15;
  const int krow = (lane >> 4) << 3;

  f32x4 acc[4][4] = {};

  const int sr = t >> 2;
  const int sc = (t & 3) << 3;
  const bf16_t* ga = Ab + (size_t)(m0 + sr) * K + sc;
  const bf16_t* gb = Ab + (size_t)(n0 + sr) * K + sc;
  bf16_t* lA0 = &As[wid * 512];
  bf16_t* lA1 = &As[2048 + wid * 512];
  bf16_t* lB0 = &Bs[wid * 512];
  bf16_t* lB1 = &Bs[2048 + wid * 512];
  const size_t rowskip = (size_t)64 * K;

  for (int k0 = 0; k0 < K; k0 += 32) {
    GLD16(ga + k0, lA0);
    GLD16(ga + rowskip + k0, lA1);
    GLD16(gb + k0, lB0);
    GLD16(gb + rowskip + k0, lB1);
    __syncthreads();
    bf16x8 af[4], bfr[4];
#pragma unroll
    for (int f = 0; f < 4; f++) {
      af[f] = *reinterpret_cast<const bf16x8*>(&As[(wm + f * 16 + fr) * 32 + krow]);
      bfr[f] = *reinterpret_cast<const bf16x8*>(&Bs[(wn + f * 16 + fr) * 32 + krow]);
    }
#pragma unroll
    for (int i = 0; i < 4; i++)
#pragma unroll
      for (int j = 0; j < 4; j++)
        acc[i][j] = __builtin_amdgcn_mfma_f32_16x16x32_bf16(af[i], bfr[j], acc[i][j], 0, 0, 0);
    __syncthreads();
  }

  const float* impb = imp + b * 1024;
  const int jw = (n0 + wn) >> 6;
  unsigned long long* crow = cond + (size_t)b * 1024 * 16;
  const int g = lane >> 4;
#pragma unroll
  for (int fm = 0; fm < 4; fm++) {
#pragma unroll
    for (int r = 0; r < 4; r++) {
      const int i = m0 + wm + fm * 16 + g * 4 + r;
      const float impi = impb[i];
      unsigned long long w0 = 0;
#pragma unroll
      for (int fn = 0; fn < 4; fn++) {
        const int j = n0 + wn + fn * 16 + fr;
        const float s = acc[fm][fn][r];
        const bool pred = (s > 0.85f) && (impb[j] >= impi) && (j < i);
        unsigned long long bal = __ballot(pred);
        w0 |= ((bal >> (g * 16)) & 0xFFFFull) << (fn * 16);
      }
      if (fr == 0) crow[(size_t)i * 16 + jw] = w0;
    }
  }
}

// ---------------------------------------------------------------------------
// Sequential greedy-keep scan. One block per batch.
// ---------------------------------------------------------------------------
__global__ __launch_bounds__(256) void scan_keep(const unsigned long long* __restrict__ cond,
                                                 float* __restrict__ keptF,
                                                 float* __restrict__ outMask) {
  __shared__ unsigned long long kept[16];
  __shared__ unsigned char cand[1024];
  const int b = blockIdx.x;
  const int t = threadIdx.x;
  if (t < 16) kept[t] = ~0ull;
  const unsigned long long* cb = cond + (size_t)b * 1024 * 16;

  for (int i = t; i < 1024; i += 256) {
    const int wmax = i >> 6;
    unsigned long long any = 0;
    for (int w = 0; w < wmax; w++) any |= cb[i * 16 + w];
    const unsigned long long m = (i & 63) ? ((1ull << (i & 63)) - 1ull) : 0ull;
    any |= cb[i * 16 + wmax] & m;
    cand[i] = (any != 0);
  }
  __syncthreads();

  if (t < 64) {
    for (int i = 1; i < 1024; i++) {
      if (!cand[i]) continue;
      const int wmax = i >> 6;
      unsigned long long v = 0;
      if (t <= wmax) {
        const unsigned long long m =
            (t < wmax) ? ~0ull : ((i & 63) ? ((1ull << (i & 63)) - 1ull) : 0ull);
        v = cb[i * 16 + t] & kept[t] & m;
      }
      const bool sup = __any(v != 0);
      if (sup && t == 0) kept[i >> 6] &= ~(1ull << (i & 63));
    }
  }
  __syncthreads();

  for (int i = t; i < 1024; i += 256) {
    const float kv = ((kept[i >> 6] >> (i & 63)) & 1ull) ? 1.0f : 0.0f;
    keptF[b * 1024 + i] = kv;
    outMask[b * 1024 + i] = kv;
  }
}

// ---------------------------------------------------------------------------
extern "C" void kernel_launch(void* const* d_in, const int* in_sizes, int n_in,
                              void* d_out, int out_size, void* d_ws, size_t ws_size,
                              hipStream_t stream) {
  const float* seg = (const float*)d_in[0];
  const float* imp = (const float*)d_in[1];
  const float* Wsim = (const float*)d_in[2];
  const float* bsim = (const float*)d_in[3];
  const float* lng = (const float*)d_in[4];
  const float* lnb = (const float*)d_in[5];
  const float* Wd1 = (const float*)d_in[6];
  const float* bd1 = (const float*)d_in[7];
  const float* Wd2 = (const float*)d_in[8];
  const float* bd2 = (const float*)d_in[9];

  char* w = (char*)d_ws;
  bf16_t* A1 = (bf16_t*)w;  w += (size_t)8192 * 4096 * 2;   // 64 MB
  bf16_t* W1T = (bf16_t*)w; w += (size_t)4096 * 4096 * 2;   // 32 MB
  bf16_t* W2T = (bf16_t*)w; w += (size_t)4096 * 2048 * 2;   // 16 MB
  bf16_t* Nrm = (bf16_t*)w; w += (size_t)8192 * 2048 * 2;   // 32 MB
  bf16_t* Hb = (bf16_t*)w;  w += (size_t)8192 * 2048 * 2;   // 32 MB
  unsigned long long* cond = (unsigned long long*)w; w += (size_t)8 * 1024 * 16 * 8;  // 1 MB
  float* keptF = (float*)w; w += (size_t)8192 * 4;

  float* X = (float*)d_out;  // 8192x4096 f32 scratch, overwritten by GEMM2
  float* outMask = (float*)d_out + (size_t)8192 * 4096;

  conv_bf16<<<4096, 256, 0, stream>>>(seg, A1, 8192 * 512);
  transpose_conv<<<2048, 256, 0, stream>>>(Wsim, W1T, 4096, 2048, 4096);
  transpose_conv<<<2048, 256, 0, stream>>>(Wd1, W1T + (size_t)2048 * 4096, 4096, 2048, 4096);
  transpose_conv<<<2048, 256, 0, stream>>>(Wd2, W2T, 2048, 4096, 2048);

  gemm256<0><<<512, 512, 0, stream>>>(A1, W1T, X, nullptr, nullptr, 8192, 4096, 4096);
  epilogue1<<<8192, 256, 0, stream>>>(X, imp, bsim, lng, lnb, bd1, Nrm, Hb);
  sim_gemm<<<288, 256, 0, stream>>>(Nrm, imp, cond);
  scan_keep<<<8, 256, 0, stream>>>(cond, keptF, outMask);
  gemm256<1><<<512, 512, 0, stream>>>(Hb, W2T, (float*)d_out, bd2, keptF, 8192, 4096, 2048);
}

// Round 4
// 828.677 us; speedup vs baseline: 1.2902x; 1.0113x over previous
//
#include <hip/hip_runtime.h>

typedef __bf16 bf16_t;
typedef __attribute__((ext_vector_type(8))) __bf16 bf16x8;
typedef __attribute__((ext_vector_type(4))) float f32x4;

#define GLD16(gptr, lptr)                                                              \
  __builtin_amdgcn_global_load_lds((const __attribute__((address_space(1))) void*)(gptr), \
                                   (__attribute__((address_space(3))) void*)(lptr), 16, 0, 0)

#define BAR() __builtin_amdgcn_s_barrier()
#define WAIT_LGKM0()                                      \
  do {                                                    \
    asm volatile("s_waitcnt lgkmcnt(0)" ::: "memory");    \
    __builtin_amdgcn_sched_barrier(0);                    \
  } while (0)
#define WAIT_VM2() asm volatile("s_waitcnt vmcnt(2)" ::: "memory")
#define WAIT_VM4() asm volatile("s_waitcnt vmcnt(4)" ::: "memory")
#define WAIT_VM0() asm volatile("s_waitcnt vmcnt(0)" ::: "memory")
#define PRIO1() __builtin_amdgcn_s_setprio(1)
#define PRIO0() __builtin_amdgcn_s_setprio(0)

__device__ __forceinline__ float gelu_f(float x) {
  return 0.5f * x * (1.0f + erff(x * 0.7071067811865476f));
}

// b0 = row-base + swizzled col for k-half 0, b1 = same for k-half 1 (col ^ 64)
__device__ __forceinline__ void ld_a4(bf16x8 (&a)[4][2], const char* b0, const char* b1) {
#pragma unroll
  for (int f = 0; f < 4; f++) {
    a[f][0] = *reinterpret_cast<const bf16x8*>(b0 + f * 2048);
    a[f][1] = *reinterpret_cast<const bf16x8*>(b1 + f * 2048);
  }
}

__device__ __forceinline__ void ld_b2(bf16x8 (&b)[2][2], const char* b0, const char* b1) {
#pragma unroll
  for (int f = 0; f < 2; f++) {
    b[f][0] = *reinterpret_cast<const bf16x8*>(b0 + f * 2048);
    b[f][1] = *reinterpret_cast<const bf16x8*>(b1 + f * 2048);
  }
}

template <int MH, int NH>
__device__ __forceinline__ void mm16(f32x4 (&acc)[8][4], const bf16x8 (&a)[4][2],
                                     const bf16x8 (&b)[2][2]) {
#pragma unroll
  for (int i = 0; i < 4; i++)
#pragma unroll
    for (int j = 0; j < 2; j++)
#pragma unroll
      for (int s = 0; s < 2; s++)
        acc[MH * 4 + i][NH * 2 + j] = __builtin_amdgcn_mfma_f32_16x16x32_bf16(
            a[i][s], b[j][s], acc[MH * 4 + i][NH * 2 + j], 0, 0, 0);
}

__device__ __forceinline__ void stage2(const bf16_t* src, char* ldst, size_t rowskip) {
  GLD16(src, ldst);
  GLD16(src + rowskip, ldst + 8192);
}

// ---------------------------------------------------------------------------
// 256x256 8-phase bf16 GEMM, C = A(MxK) * BT(NxK)^T.  BK=64, 8 waves (2x4).
// One-phase-ahead reads: phase p = [lgkm0; MFMA_p; STG_p; reads_{p+1};
// (vmcnt(2) at P3/P7); BAR].  Swizzle byte ^= ((row&7)<<4), linear LDS dest +
// inverse-swizzled global source + swizzled ds_read.
// EPI 1: f32 out, (acc+bias[col])*rowscale[row].  EPI 2: bf16 out, plain.
// ---------------------------------------------------------------------------
template <int EPI>
__global__ __launch_bounds__(512, 2) void gemm256(const bf16_t* __restrict__ A,
                                                  const bf16_t* __restrict__ BT,
                                                  float* __restrict__ C,
                                                  const float* __restrict__ bias,
                                                  const float* __restrict__ rowscale,
                                                  int M, int N, int K) {
  __shared__ char smem[131072];
  const int NKT = K >> 6;
  const int niter = NKT >> 1;

  const int nbn = N >> 8;
  int bid = blockIdx.x;
  const int cpx = gridDim.x >> 3;  // nwg % 8 == 0 guaranteed by launch
  bid = (bid & 7) * cpx + (bid >> 3);
  const int m0 = (bid / nbn) << 8, n0 = (bid % nbn) << 8;

  const int t = threadIdx.x;
  const int lane = t & 63, wid = t >> 6;
  const int wr = wid >> 2, wc = wid & 3;
  const int fr = lane & 15, kq = lane >> 4;
  const int c0 = (kq ^ (fr & 7)) << 4;  // swizzled col byte, k-half 0
  const int c1 = c0 ^ 64;               // k-half 1

  const char* aB0 = smem + wr * 16384 + fr * 128 + c0;
  const char* aB1 = smem + wr * 16384 + fr * 128 + c1;
  const char* bB0 = smem + 65536 + (wc >> 1) * 16384 + ((wc & 1) * 64 + fr) * 128 + c0;
  const char* bB1 = smem + 65536 + (wc >> 1) * 16384 + ((wc & 1) * 64 + fr) * 128 + c1;

  // stage source: LDS dest linear t*16; source byte = (t*16) ^ (((t>>3)&7)<<4)
  const int sr0 = t >> 3;
  const int scol = ((t & 7) ^ (sr0 & 7)) * 8;
  const bf16_t* gA = A + (size_t)(m0 + sr0) * K + scol;
  const bf16_t* gB = BT + (size_t)(n0 + sr0) * K + scol;
  const size_t rskip = (size_t)64 * K;
  char* ldA = smem + t * 16;
  char* ldB = smem + 65536 + t * 16;

#define STG_A(kc, bb, h) stage2(gA + (size_t)(h)*128 * K + (size_t)(kc)*64, ldA + ((bb)*2 + (h)) * 16384, rskip)
#define STG_B(kc, bb, h) stage2(gB + (size_t)(h)*128 * K + (size_t)(kc)*64, ldB + ((bb)*2 + (h)) * 16384, rskip)

  f32x4 acc[8][4] = {};
  bf16x8 a[4][2], b0[2][2], b1[2][2];

  // prologue: stage c0.B, c0.A (buf0), c1.B (buf1); publish buf0; preread P1 operands
  STG_B(0, 0, 0); STG_B(0, 0, 1); STG_A(0, 0, 0); STG_A(0, 0, 1);
  STG_B(1, 1, 0); STG_B(1, 1, 1);
  WAIT_VM4();  // completes B(c0),A(c0); leaves B(c1) x4 outstanding
  BAR();
  ld_a4(a, aB0, aB1);   // a_lo(c0)
  ld_b2(b0, bB0, bB1);  // b0(c0)

  for (int it = 0; it < niter; ++it) {
    const int c1k = 2 * it + 1;
    const int c2k = (2 * it + 2 < NKT) ? 2 * it + 2 : NKT - 1;
    const int c3k = (2 * it + 3 < NKT) ? 2 * it + 3 : NKT - 1;

    // P1: MFMA c0 (0,0)
    WAIT_LGKM0();
    PRIO1(); mm16<0, 0>(acc, a, b0); PRIO0();
    STG_A(c1k, 1, 0);
    ld_b2(b1, bB0 + 4096, bB1 + 4096);  // b1(c0)
    BAR();
    // P2: (0,1)
    WAIT_LGKM0();
    PRIO1(); mm16<0, 1>(acc, a, b1); PRIO0();
    STG_A(c1k, 1, 1);
    ld_a4(a, aB0 + 8192, aB1 + 8192);  // a_hi(c0)
    BAR();
    // P3: (1,0)
    WAIT_LGKM0();
    PRIO1(); mm16<1, 0>(acc, a, b0); PRIO0();
    STG_B(c2k, 0, 0);
    WAIT_VM2();  // completes B(c1),A(c1) -> buf1 published at next BAR
    BAR();
    // P4: (1,1)
    WAIT_LGKM0();
    PRIO1(); mm16<1, 1>(acc, a, b1); PRIO0();
    STG_B(c2k, 0, 1);
    ld_a4(a, aB0 + 32768, aB1 + 32768);   // a_lo(c1) buf1
    ld_b2(b0, bB0 + 32768, bB1 + 32768);  // b0(c1)
    BAR();
    // P5: c1 (0,0)
    WAIT_LGKM0();
    PRIO1(); mm16<0, 0>(acc, a, b0); PRIO0();
    STG_A(c2k, 0, 0);
    ld_b2(b1, bB0 + 36864, bB1 + 36864);  // b1(c1)
    BAR();
    // P6: (0,1)
    WAIT_LGKM0();
    PRIO1(); mm16<0, 1>(acc, a, b1); PRIO0();
    STG_A(c2k, 0, 1);
    ld_a4(a, aB0 + 40960, aB1 + 40960);  // a_hi(c1)
    BAR();
    // P7: (1,0)
    WAIT_LGKM0();
    PRIO1(); mm16<1, 0>(acc, a, b0); PRIO0();
    STG_B(c3k, 1, 0);
    WAIT_VM2();  // completes B(c2),A(c2) -> buf0 published at next BAR
    BAR();
    // P8: (1,1)
    WAIT_LGKM0();
    PRIO1(); mm16<1, 1>(acc, a, b1); PRIO0();
    STG_B(c3k, 1, 1);
    ld_a4(a, aB0, aB1);   // a_lo(c2) buf0
    ld_b2(b0, bB0, bB1);  // b0(c2)
    BAR();
  }
  WAIT_VM0();

#undef STG_A
#undef STG_B

  const int r0 = kq * 4;
#pragma unroll
  for (int i = 0; i < 8; i++) {
    const int row = m0 + wr * 128 + i * 16 + r0;
#pragma unroll
    for (int j = 0; j < 4; j++) {
      const int col = n0 + wc * 64 + j * 16 + fr;
#pragma unroll
      for (int r = 0; r < 4; r++) {
        float v = acc[i][j][r];
        if (EPI == 1) {
          v = (v + bias[col]) * rowscale[row + r];
          C[(size_t)(row + r) * N + col] = v;
        } else {
          reinterpret_cast<bf16_t*>(C)[(size_t)(row + r) * N + col] = (bf16_t)v;
        }
      }
    }
  }
}

// ---------------------------------------------------------------------------
// f32 -> bf16 convert (vectorized, grid-stride). n8 = count of 8-elem groups.
// ---------------------------------------------------------------------------
__global__ __launch_bounds__(256) void conv_bf16(const float* __restrict__ in,
                                                 bf16_t* __restrict__ out, int n8) {
  for (int idx = blockIdx.x * 256 + threadIdx.x; idx < n8; idx += gridDim.x * 256) {
    const float4* p = reinterpret_cast<const float4*>(in + (size_t)idx * 8);
    float4 a = p[0], b = p[1];
    bf16x8 v;
    v[0] = (bf16_t)a.x; v[1] = (bf16_t)a.y; v[2] = (bf16_t)a.z; v[3] = (bf16_t)a.w;
    v[4] = (bf16_t)b.x; v[5] = (bf16_t)b.y; v[6] = (bf16_t)b.z; v[7] = (bf16_t)b.w;
    *reinterpret_cast<bf16x8*>(out + (size_t)idx * 8) = v;
  }
}

// ---------------------------------------------------------------------------
// Tiled transpose + f32->bf16: dst[n*dstStride + k] = src[k*N + n]
// ---------------------------------------------------------------------------
__global__ __launch_bounds__(256) void transpose_conv(const float* __restrict__ src,
                                                      bf16_t* __restrict__ dst, int K,
                                                      int N, int dstStride) {
  __shared__ float lds[64][65];
  const int ntn = N >> 6;
  const int tile = blockIdx.x;
  const int tk = tile / ntn, tn = tile % ntn;
  const int k0 = tk << 6, n0 = tn << 6;
  const int t = threadIdx.x;
#pragma unroll
  for (int q = 0; q < 16; q++) {
    int idx = q * 256 + t;
    int kk = idx >> 6, nn = idx & 63;
    lds[kk][nn] = src[(size_t)(k0 + kk) * N + n0 + nn];
  }
  __syncthreads();
#pragma unroll
  for (int q = 0; q < 16; q++) {
    int idx = q * 256 + t;
    int nn = idx >> 6, kk = idx & 63;
    dst[(size_t)(n0 + nn) * dstStride + k0 + kk] = (bf16_t)lds[kk][nn];
  }
}

// ---------------------------------------------------------------------------
// Row epilogue after GEMM1 (X now bf16).
// ---------------------------------------------------------------------------
__global__ __launch_bounds__(256) void epilogue1(const bf16_t* __restrict__ X,
                                                 const float* __restrict__ imp,
                                                 const float* __restrict__ b_sim,
                                                 const float* __restrict__ ln_g,
                                                 const float* __restrict__ ln_b,
                                                 const float* __restrict__ b_d1,
                                                 bf16_t* __restrict__ Nrm,
                                                 bf16_t* __restrict__ Hbuf) {
  __shared__ float red[8];
  const int row = blockIdx.x;
  const int t = threadIdx.x;
  const int lane = t & 63, wid = t >> 6;
  const bf16_t* xr = X + (size_t)row * 4096;
  const int c0 = t * 8;

  float g[8];
  float s1 = 0.f, s2 = 0.f;
  {
    bf16x8 xv = *reinterpret_cast<const bf16x8*>(xr + c0);
#pragma unroll
    for (int q = 0; q < 8; q++) {
      float v = (float)xv[q] + b_sim[c0 + q];
      float gv = gelu_f(v);
      g[q] = gv;
      s1 += gv;
      s2 += gv * gv;
    }
  }
#pragma unroll
  for (int o = 32; o > 0; o >>= 1) {
    s1 += __shfl_down(s1, o);
    s2 += __shfl_down(s2, o);
  }
  if (lane == 0) { red[wid] = s1; red[4 + wid] = s2; }
  __syncthreads();
  s1 = red[0] + red[1] + red[2] + red[3];
  s2 = red[4] + red[5] + red[6] + red[7];
  __syncthreads();

  const float mu = s1 * (1.0f / 2048.0f);
  const float var = s2 * (1.0f / 2048.0f) - mu * mu;
  const float rstd = rsqrtf(var + 1e-5f);

  float y[8];
  float s3 = 0.f;
#pragma unroll
  for (int q = 0; q < 8; q++) {
    float yv = (g[q] - mu) * rstd * ln_g[c0 + q] + ln_b[c0 + q];
    y[q] = yv;
    s3 += yv * yv;
  }
#pragma unroll
  for (int o = 32; o > 0; o >>= 1) s3 += __shfl_down(s3, o);
  if (lane == 0) red[wid] = s3;
  __syncthreads();
  s3 = red[0] + red[1] + red[2] + red[3];

  const float scale = 1.0f / (sqrtf(s3) + 1e-8f);
  bf16x8 nv;
#pragma unroll
  for (int q = 0; q < 8; q++) nv[q] = (bf16_t)(y[q] * scale);
  *reinterpret_cast<bf16x8*>(Nrm + (size_t)row * 2048 + c0) = nv;

  const float ir = imp[row];
  bf16x8 xv2 = *reinterpret_cast<const bf16x8*>(xr + 2048 + c0);
  bf16x8 hv;
#pragma unroll
  for (int q = 0; q < 8; q++) {
    float v = (float)xv2[q] * ir + b_d1[c0 + q];
    hv[q] = (bf16_t)gelu_f(v);
  }
  *reinterpret_cast<bf16x8*>(Hbuf + (size_t)row * 2048 + c0) = hv;
}

// ---------------------------------------------------------------------------
// Batched sim GEMM over lower-triangular 128x128 tiles -> condition bitmasks.
// ---------------------------------------------------------------------------
__global__ __launch_bounds__(256) void sim_gemm(const bf16_t* __restrict__ Nrm,
                                                const float* __restrict__ imp,
                                                unsigned long long* __restrict__ cond) {
  __shared__ bf16_t As[128 * 32];
  __shared__ bf16_t Bs[128 * 32];

  const int b = blockIdx.x / 36;
  const int tt = blockIdx.x % 36;
  int ti = 0;
  while ((ti + 1) * (ti + 2) / 2 <= tt) ti++;
  const int tj = tt - ti * (ti + 1) / 2;

  const bf16_t* Ab = Nrm + (size_t)b * 1024 * 2048;
  const int K = 2048;
  const int m0 = ti << 7, n0 = tj << 7;

  const int t = threadIdx.x;
  const int lane = t & 63, wid = t >> 6;
  const int wm = (wid >> 1) << 6, wn = (wid & 1) << 6;
  const int fr = lane & 15;
  const int krow = (lane >> 4) << 3;

  f32x4 acc[4][4] = {};

  const int sr = t >> 2;
  const int sc = (t & 3) << 3;
  const bf16_t* ga = Ab + (size_t)(m0 + sr) * K + sc;
  const bf16_t* gb = Ab + (size_t)(n0 + sr) * K + sc;
  bf16_t* lA0 = &As[wid * 512];
  bf16_t* lA1 = &As[2048 + wid * 512];
  bf16_t* lB0 = &Bs[wid * 512];
  bf16_t* lB1 = &Bs[2048 + wid * 512];
  const size_t rowskip = (size_t)64 * K;

  for (int k0 = 0; k0 < K; k0 += 32) {
    GLD16(ga + k0, lA0);
    GLD16(ga + rowskip + k0, lA1);
    GLD16(gb + k0, lB0);
    GLD16(gb + rowskip + k0, lB1);
    __syncthreads();
    bf16x8 af[4], bfr[4];
#pragma unroll
    for (int f = 0; f < 4; f++) {
      af[f] = *reinterpret_cast<const bf16x8*>(&As[(wm + f * 16 + fr) * 32 + krow]);
      bfr[f] = *reinterpret_cast<const bf16x8*>(&Bs[(wn + f * 16 + fr) * 32 + krow]);
    }
#pragma unroll
    for (int i = 0; i < 4; i++)
#pragma unroll
      for (int j = 0; j < 4; j++)
        acc[i][j] = __builtin_amdgcn_mfma_f32_16x16x32_bf16(af[i], bfr[j], acc[i][j], 0, 0, 0);
    __syncthreads();
  }

  const float* impb = imp + b * 1024;
  const int jw = (n0 + wn) >> 6;
  unsigned long long* crow = cond + (size_t)b * 1024 * 16;
  const int g = lane >> 4;
#pragma unroll
  for (int fm = 0; fm < 4; fm++) {
#pragma unroll
    for (int r = 0; r < 4; r++) {
      const int i = m0 + wm + fm * 16 + g * 4 + r;
      const float impi = impb[i];
      unsigned long long w0 = 0;
#pragma unroll
      for (int fn = 0; fn < 4; fn++) {
        const int j = n0 + wn + fn * 16 + fr;
        const float s = acc[fm][fn][r];
        const bool pred = (s > 0.85f) && (impb[j] >= impi) && (j < i);
        unsigned long long bal = __ballot(pred);
        w0 |= ((bal >> (g * 16)) & 0xFFFFull) << (fn * 16);
      }
      if (fr == 0) crow[(size_t)i * 16 + jw] = w0;
    }
  }
}

// ---------------------------------------------------------------------------
// Sequential greedy-keep scan. One block per batch.
// ---------------------------------------------------------------------------
__global__ __launch_bounds__(256) void scan_keep(const unsigned long long* __restrict__ cond,
                                                 float* __restrict__ keptF,
                                                 float* __restrict__ outMask) {
  __shared__ unsigned long long kept[16];
  __shared__ unsigned char cand[1024];
  const int b = blockIdx.x;
  const int t = threadIdx.x;
  if (t < 16) kept[t] = ~0ull;
  const unsigned long long* cb = cond + (size_t)b * 1024 * 16;

  for (int i = t; i < 1024; i += 256) {
    const int wmax = i >> 6;
    unsigned long long any = 0;
    for (int w = 0; w < wmax; w++) any |= cb[i * 16 + w];
    const unsigned long long m = (i & 63) ? ((1ull << (i & 63)) - 1ull) : 0ull;
    any |= cb[i * 16 + wmax] & m;
    cand[i] = (any != 0);
  }
  __syncthreads();

  if (t < 64) {
    for (int i = 1; i < 1024; i++) {
      if (!cand[i]) continue;
      const int wmax = i >> 6;
      unsigned long long v = 0;
      if (t <= wmax) {
        const unsigned long long m =
            (t < wmax) ? ~0ull : ((i & 63) ? ((1ull << (i & 63)) - 1ull) : 0ull);
        v = cb[i * 16 + t] & kept[t] & m;
      }
      const bool sup = __any(v != 0);
      if (sup && t == 0) kept[i >> 6] &= ~(1ull << (i & 63));
    }
  }
  __syncthreads();

  for (int i = t; i < 1024; i += 256) {
    const float kv = ((kept[i >> 6] >> (i & 63)) & 1ull) ? 1.0f : 0.0f;
    keptF[b * 1024 + i] = kv;
    outMask[b * 1024 + i] = kv;
  }
}

// ---------------------------------------------------------------------------
extern "C" void kernel_launch(void* const* d_in, const int* in_sizes, int n_in,
                              void* d_out, int out_size, void* d_ws, size_t ws_size,
                              hipStream_t stream) {
  const float* seg = (const float*)d_in[0];
  const float* imp = (const float*)d_in[1];
  const float* Wsim = (const float*)d_in[2];
  const float* bsim = (const float*)d_in[3];
  const float* lng = (const float*)d_in[4];
  const float* lnb = (const float*)d_in[5];
  const float* Wd1 = (const float*)d_in[6];
  const float* bd1 = (const float*)d_in[7];
  const float* Wd2 = (const float*)d_in[8];
  const float* bd2 = (const float*)d_in[9];

  char* w = (char*)d_ws;
  bf16_t* A1 = (bf16_t*)w;  w += (size_t)8192 * 4096 * 2;   // 64 MB
  bf16_t* W1T = (bf16_t*)w; w += (size_t)4096 * 4096 * 2;   // 32 MB
  bf16_t* W2T = (bf16_t*)w; w += (size_t)4096 * 2048 * 2;   // 16 MB
  bf16_t* Nrm = (bf16_t*)w; w += (size_t)8192 * 2048 * 2;   // 32 MB
  bf16_t* Hb = (bf16_t*)w;  w += (size_t)8192 * 2048 * 2;   // 32 MB
  unsigned long long* cond = (unsigned long long*)w; w += (size_t)8 * 1024 * 16 * 8;  // 1 MB
  float* keptF = (float*)w; w += (size_t)8192 * 4;

  bf16_t* Xb = (bf16_t*)d_out;  // 8192x4096 bf16 scratch, overwritten by GEMM2
  float* outMask = (float*)d_out + (size_t)8192 * 4096;

  conv_bf16<<<4096, 256, 0, stream>>>(seg, A1, 8192 * 512);
  transpose_conv<<<2048, 256, 0, stream>>>(Wsim, W1T, 4096, 2048, 4096);
  transpose_conv<<<2048, 256, 0, stream>>>(Wd1, W1T + (size_t)2048 * 4096, 4096, 2048, 4096);
  transpose_conv<<<2048, 256, 0, stream>>>(Wd2, W2T, 2048, 4096, 2048);

  gemm256<2><<<512, 512, 0, stream>>>(A1, W1T, (float*)Xb, nullptr, nullptr, 8192, 4096, 4096);
  epilogue1<<<8192, 256, 0, stream>>>(Xb, imp, bsim, lng, lnb, bd1, Nrm, Hb);
  sim_gemm<<<288, 256, 0, stream>>>(Nrm, imp, cond);
  scan_keep<<<8, 256, 0, stream>>>(cond, keptF, outMask);
  gemm256<1><<<512, 512, 0, stream>>>(Hb, W2T, (float*)d_out, bd2, keptF, 8192, 4096, 2048);
}